// Round 1
// baseline (1286.957 us; speedup 1.0000x reference)
//
#include <hip/hip_runtime.h>

#define B 8
#define NOBJ 128
#define NATTR 4
#define T 12
#define MC 2048
#define E 128
#define IDD 64
#define AD 64
#define HD 256
#define C 2176
#define NCH 17
#define CJ 128

// ---------------- setup kernels ----------------

__global__ void k_build(const int* __restrict__ scene,
                        const float* __restrict__ aein, const float* __restrict__ aeout,
                        const float* __restrict__ aeid,
                        const float* __restrict__ cein, const float* __restrict__ ceout,
                        const float* __restrict__ ceid,
                        const float* __restrict__ att_init,
                        float* __restrict__ dendron, float* __restrict__ axon,
                        float* __restrict__ identity, float* __restrict__ attention) {
  int bj = blockIdx.x;          // b*C + j
  int b = bj / C, j = bj % C;
  int e = threadIdx.x;          // 0..127
  float din, dout, did = 0.f;
  if (j < MC) {
    din  = cein[j * E + e];
    dout = ceout[j * E + e];
    if (e < IDD) did = ceid[j * IDD + e];
  } else {
    int obj = j - MC;
    float sIn = 0.f, sOut = 0.f, sId = 0.f;
    for (int a = 0; a < NATTR; a++) {
      int s = scene[(b * NOBJ + obj) * NATTR + a];
      float m = (s != -1) ? 1.f : 0.f;
      int idx = s + 1;
      sIn  += aein[idx * E + e] * m;
      sOut += aeout[idx * E + e] * m;
      if (e < IDD) sId += aeid[idx * IDD + e] * m;
    }
    din = sIn; dout = sOut; did = sId;
  }
  dendron[(size_t)(b * C + j) * E + e] = din;
  axon[(size_t)(b * C + j) * E + e]    = dout;
  if (e < IDD) {
    identity[(size_t)(b * C + j) * IDD + e]  = did;
    attention[(size_t)(b * C + j) * AD + e]  = att_init[e];
  }
}

__global__ void k_transpose(const float* __restrict__ w1, const float* __restrict__ w2,
                            float* __restrict__ w1T, float* __restrict__ w2T) {
  int idx = blockIdx.x * blockDim.x + threadIdx.x;
  if (idx < HD * E) { int k = idx / E;  int d = idx % E;  w1T[d * HD + k] = w1[k * E + d]; }
  if (idx < HD * AD) { int a = idx / HD; int k = idx % HD; w2T[k * AD + a] = w2[a * HD + k]; }
}

// sequential meta scan (tiny): one block per batch
__global__ void k_meta(const int* __restrict__ prog_op, const int* __restrict__ prog_arg,
                       const float* __restrict__ ceout,
                       const float* __restrict__ mw1, const float* __restrict__ mb1,
                       const float* __restrict__ mw2, const float* __restrict__ mb2,
                       const float* __restrict__ att_init, float* __restrict__ meta_all) {
  int b = blockIdx.x;
  __shared__ float x[192];
  __shared__ float h[HD];
  __shared__ float meta[AD];
  int tid = threadIdx.x;
  if (tid < AD) meta[tid] = att_init[tid];
  __syncthreads();
  for (int t = 0; t < T; t++) {
    int arg = prog_arg[b * T + t];
    if (tid < AD) x[tid] = meta[tid];
    else if (tid < 192) x[tid] = ceout[arg * E + (tid - 64)];
    __syncthreads();
    float s = mb1[tid];
    for (int c = 0; c < 192; c++) s += x[c] * mw1[tid * 192 + c];
    h[tid] = fmaxf(s, 0.f);
    __syncthreads();
    if (tid < AD) {
      float o = mb2[tid];
      for (int k = 0; k < HD; k++) o += h[k] * mw2[tid * HD + k];
      float m = (prog_op[b * T + t] == 0) ? 1.f : 0.f;
      float nm = m * o + (1.f - m) * meta[tid];
      meta[tid] = nm;
      meta_all[(t * B + b) * AD + tid] = nm;
    }
    __syncthreads();
  }
}

// proj[t,b,i] = dot(arguments[b,t], axon[b,i]) / E ; one wave per (b,i)
__global__ void k_proj(const int* __restrict__ prog_arg, const float* __restrict__ ceout,
                       const float* __restrict__ axon, float* __restrict__ proj_all) {
  int gid = blockIdx.x * 4 + (threadIdx.x >> 6);
  int lane = threadIdx.x & 63;
  if (gid >= B * C) return;
  int b = gid / C, i = gid % C;
  float a0 = axon[(size_t)(b * C + i) * E + lane];
  float a1 = axon[(size_t)(b * C + i) * E + 64 + lane];
  for (int t = 0; t < T; t++) {
    int arg = prog_arg[b * T + t];
    float p = a0 * ceout[arg * E + lane] + a1 * ceout[arg * E + 64 + lane];
    for (int off = 1; off < 64; off <<= 1) p += __shfl_xor(p, off, 64);
    if (lane == 0) proj_all[(size_t)(t * B + b) * C + i] = p * (1.f / E);
  }
}

// ---------------- per-step kernels ----------------

// partial M[b][e][d] over one j-chunk: M = sum_j axon[j][e] * amean[j] * ia[j][d]
__global__ __launch_bounds__(256) void k_partM(const float* __restrict__ axon,
                                               const float* __restrict__ identity,
                                               const float* __restrict__ attention,
                                               float* __restrict__ Mpart) {
  int blk = blockIdx.x;               // b*NCH + ch
  int b = blk / NCH, ch = blk % NCH;
  int j0 = ch * CJ;
  __shared__ float axs[CJ][E];        // 64 KB
  __shared__ float sia[CJ][E];        // 64 KB
  __shared__ float am[CJ];
  int tid = threadIdx.x;
  if (tid < CJ) {
    float s = 0.f;
    const float* ap = attention + (size_t)(b * C + j0 + tid) * AD;
    for (int a = 0; a < AD; a++) s += ap[a];
    am[tid] = s * (1.f / AD);
  }
  for (int idx = tid; idx < CJ * E; idx += 256) {
    int j = idx >> 7, e = idx & 127;
    axs[j][e] = axon[(size_t)(b * C + j0 + j) * E + e];
  }
  __syncthreads();
  for (int idx = tid; idx < CJ * E; idx += 256) {
    int j = idx >> 7, d = idx & 127;
    float v = (d < IDD) ? identity[(size_t)(b * C + j0 + j) * IDD + d]
                        : attention[(size_t)(b * C + j0 + j) * AD + (d - IDD)];
    sia[j][d] = v * am[j];
  }
  __syncthreads();
  int d = tid & 127;
  int e0 = (tid >> 7) * 64;
  float acc[64];
  #pragma unroll
  for (int e = 0; e < 64; e++) acc[e] = 0.f;
  for (int j = 0; j < CJ; j++) {
    float s = sia[j][d];
    const float4* arow = (const float4*)&axs[j][e0];
    #pragma unroll
    for (int e4 = 0; e4 < 16; e4++) {
      float4 v = arow[e4];
      acc[e4 * 4 + 0] += v.x * s;
      acc[e4 * 4 + 1] += v.y * s;
      acc[e4 * 4 + 2] += v.z * s;
      acc[e4 * 4 + 3] += v.w * s;
    }
  }
  float* mp = Mpart + (size_t)(b * NCH + ch) * E * E;
  #pragma unroll
  for (int e = 0; e < 64; e++) mp[(e0 + e) * E + d] = acc[e];
}

__global__ void k_reduceM(const float* __restrict__ Mpart, float* __restrict__ M) {
  int idx = blockIdx.x * 256 + threadIdx.x;   // B*E*E = 131072
  int b = idx >> 14, ed = idx & 16383;
  float s = 0.f;
  const float* p = Mpart + (size_t)b * NCH * E * E + ed;
  for (int c = 0; c < NCH; c++) s += p[c * E * E];
  M[idx] = s;
}

// fused: gathered = dendron@M/C ; MLP ; insert/transfer ; state update ; hist writes
__global__ __launch_bounds__(256) void k_row(
    int t, const float* __restrict__ dendron, const float* __restrict__ M,
    const float* __restrict__ w1T, const float* __restrict__ b1,
    const float* __restrict__ w2T, const float* __restrict__ b2,
    const float* __restrict__ proj_all, const float* __restrict__ meta_all,
    const int* __restrict__ prog_op, float* __restrict__ attention,
    float* __restrict__ att_hist, float* __restrict__ ins_hist, float* __restrict__ trans_hist) {
  int blk = blockIdx.x;
  int b = blk / (C / 16), tile = blk % (C / 16);
  int i0 = tile * 16;
  __shared__ float dnd[16][E];
  __shared__ float g[16][E];
  __shared__ float h[16][HD];
  __shared__ float projL[16];
  __shared__ float metaL[AD];
  int tid = threadIdx.x;
  for (int idx = tid; idx < 16 * E; idx += 256) {
    int r = idx >> 7, e = idx & 127;
    dnd[r][e] = dendron[(size_t)(b * C + i0 + r) * E + e];
  }
  if (tid < 16) projL[tid] = proj_all[(size_t)(t * B + b) * C + i0 + tid];
  else if (tid >= 32 && tid < 96) metaL[tid - 32] = meta_all[(t * B + b) * AD + (tid - 32)];
  __syncthreads();
  // phase A: gathered
  {
    int d = tid & 127, half = tid >> 7, r0 = half * 8;
    float acc[8];
    #pragma unroll
    for (int r = 0; r < 8; r++) acc[r] = 0.f;
    const float* Mb = M + (size_t)b * E * E + d;
    for (int e = 0; e < E; e++) {
      float m = Mb[e * E];
      #pragma unroll
      for (int r = 0; r < 8; r++) acc[r] += dnd[r0 + r][e] * m;
    }
    #pragma unroll
    for (int r = 0; r < 8; r++) g[r0 + r][d] = acc[r] * (1.f / C);
  }
  __syncthreads();
  // phase B: hidden layer
  {
    int k = tid;
    float acc[16];
    float bb = b1[k];
    #pragma unroll
    for (int r = 0; r < 16; r++) acc[r] = bb;
    for (int d = 0; d < E; d++) {
      float w = w1T[d * HD + k];
      #pragma unroll
      for (int r = 0; r < 16; r++) acc[r] += g[r][d] * w;
    }
    #pragma unroll
    for (int r = 0; r < 16; r++) h[r][k] = fmaxf(acc[r], 0.f);
  }
  __syncthreads();
  // phase C: output layer + update + writes
  {
    int a = tid & 63, rg = tid >> 6;
    float acc[4];
    float bb = b2[a];
    #pragma unroll
    for (int r = 0; r < 4; r++) acc[r] = bb;
    for (int k = 0; k < HD; k++) {
      float w = w2T[k * AD + a];
      #pragma unroll
      for (int r = 0; r < 4; r++) acc[r] += h[rg * 4 + r][k] * w;
    }
    int op = prog_op[b * T + t];
    float insF = (op == 1) ? 1.f : 0.f, trF = (op == 2) ? 1.f : 0.f;
    #pragma unroll
    for (int r = 0; r < 4; r++) {
      int row = rg * 4 + r;
      float transfer = acc[r] + g[row][IDD + a];
      float insert = metaL[a] * projL[row];
      size_t ai = (size_t)(b * C + i0 + row) * AD + a;
      float attv = attention[ai] + insF * insert + trF * transfer;
      attv = (attv >= 0.f) ? attv : 0.01f * attv;
      attv = fminf(fmaxf(attv, -1.f), 2.f);
      attention[ai] = attv;
      size_t hi = (((size_t)t * B + b) * C + i0 + row) * AD + a;
      att_hist[hi] = attv;
      ins_hist[hi] = insert;
      trans_hist[hi] = transfer;
    }
  }
}

// ---------------- final softmax ----------------
__global__ void k_softmax(const float* __restrict__ attention, float* __restrict__ out) {
  int b = blockIdx.x;
  __shared__ float am[C];
  __shared__ float red[256];
  int tid = threadIdx.x;
  for (int i = tid; i < C; i += 256) {
    float s = 0.f;
    const float* p = attention + (size_t)(b * C + i) * AD;
    for (int a = 0; a < AD; a++) s += p[a];
    am[i] = s * (1.f / AD);
  }
  __syncthreads();
  float mx = -1e30f;
  for (int i = tid; i < C; i += 256) mx = fmaxf(mx, am[i]);
  red[tid] = mx; __syncthreads();
  for (int s = 128; s > 0; s >>= 1) { if (tid < s) red[tid] = fmaxf(red[tid], red[tid + s]); __syncthreads(); }
  mx = red[0]; __syncthreads();
  float sm = 0.f;
  for (int i = tid; i < C; i += 256) sm += expf(am[i] - mx);
  red[tid] = sm; __syncthreads();
  for (int s = 128; s > 0; s >>= 1) { if (tid < s) red[tid] += red[tid + s]; __syncthreads(); }
  float lse = logf(red[0]) + mx;
  for (int i = tid; i < C; i += 256) out[(size_t)b * C + i] = am[i] - lse;
}

extern "C" void kernel_launch(void* const* d_in, const int* in_sizes, int n_in,
                              void* d_out, int out_size, void* d_ws, size_t ws_size,
                              hipStream_t stream) {
  const int* scene     = (const int*)d_in[0];
  const int* prog_op   = (const int*)d_in[1];
  const int* prog_arg  = (const int*)d_in[2];
  const float* aein    = (const float*)d_in[3];
  const float* aeout   = (const float*)d_in[4];
  const float* aeid    = (const float*)d_in[5];
  const float* cein    = (const float*)d_in[6];
  const float* ceout   = (const float*)d_in[7];
  const float* ceid    = (const float*)d_in[8];
  const float* att_init = (const float*)d_in[11];
  const float* aw1 = (const float*)d_in[12];
  const float* ab1 = (const float*)d_in[13];
  const float* aw2 = (const float*)d_in[14];
  const float* ab2 = (const float*)d_in[15];
  const float* mw1 = (const float*)d_in[16];
  const float* mb1 = (const float*)d_in[17];
  const float* mw2 = (const float*)d_in[18];
  const float* mb2 = (const float*)d_in[19];

  float* ws = (float*)d_ws;
  float* dendron   = ws;                       // B*C*E    = 2228224
  float* axon      = dendron + 2228224;        // 2228224
  float* identity  = axon + 2228224;           // B*C*IDD  = 1114112
  float* attention = identity + 1114112;       // B*C*AD   = 1114112
  float* M         = attention + 1114112;      // B*E*E    = 131072
  float* Mpart     = M + 131072;               // B*NCH*E*E= 2228224
  float* meta_all  = Mpart + 2228224;          // T*B*AD   = 6144
  float* proj_all  = meta_all + 6144;          // T*B*C    = 208896
  float* w1T       = proj_all + 208896;        // 32768
  float* w2T       = w1T + 32768;              // 16384

  float* out_sm     = (float*)d_out;
  float* att_hist   = out_sm + B * C;
  float* ins_hist   = att_hist + (size_t)T * B * C * AD;
  float* trans_hist = ins_hist + (size_t)T * B * C * AD;

  k_build<<<dim3(B * C), dim3(E), 0, stream>>>(scene, aein, aeout, aeid, cein, ceout, ceid,
                                               att_init, dendron, axon, identity, attention);
  k_transpose<<<dim3(128), dim3(256), 0, stream>>>(aw1, aw2, w1T, w2T);
  k_meta<<<dim3(B), dim3(256), 0, stream>>>(prog_op, prog_arg, ceout, mw1, mb1, mw2, mb2,
                                            att_init, meta_all);
  k_proj<<<dim3(B * C / 4), dim3(256), 0, stream>>>(prog_arg, ceout, axon, proj_all);

  for (int t = 0; t < T; t++) {
    k_partM<<<dim3(B * NCH), dim3(256), 0, stream>>>(axon, identity, attention, Mpart);
    k_reduceM<<<dim3(B * E * E / 256), dim3(256), 0, stream>>>(Mpart, M);
    k_row<<<dim3(B * (C / 16)), dim3(256), 0, stream>>>(t, dendron, M, w1T, ab1, w2T, ab2,
                                                        proj_all, meta_all, prog_op, attention,
                                                        att_hist, ins_hist, trans_hist);
  }
  k_softmax<<<dim3(B), dim3(256), 0, stream>>>(attention, out_sm);
}

// Round 2
// 1018.231 us; speedup vs baseline: 1.2639x; 1.2639x over previous
//
#include <hip/hip_runtime.h>

#define B 8
#define NOBJ 128
#define NATTR 4
#define T 12
#define MC 2048
#define E 128
#define IDD 64
#define AD 64
#define HD 256
#define C 2176

typedef short s16x8 __attribute__((ext_vector_type(8)));
typedef float f32x4 __attribute__((ext_vector_type(4)));

__device__ inline unsigned short f2b(float f) {
  union { float f; unsigned u; } v; v.f = f;
  unsigned r = v.u + 0x7FFFu + ((v.u >> 16) & 1u);
  return (unsigned short)(r >> 16);
}
__device__ inline float b2f(unsigned short u) {
  union { unsigned u; float f; } v; v.u = ((unsigned)u) << 16;
  return v.f;
}

// ---------------- setup kernels ----------------

__global__ void k_build(const int* __restrict__ scene,
                        const float* __restrict__ aein, const float* __restrict__ aeout,
                        const float* __restrict__ aeid,
                        const float* __restrict__ cein, const float* __restrict__ ceout,
                        const float* __restrict__ ceid,
                        const float* __restrict__ att_init,
                        unsigned short* __restrict__ dendron_bf, float* __restrict__ axon,
                        float* __restrict__ identity, float* __restrict__ attention) {
  int bj = blockIdx.x;          // b*C + j
  int b = bj / C, j = bj % C;
  int e = threadIdx.x;          // 0..127
  float din, dout, did = 0.f;
  if (j < MC) {
    din  = cein[j * E + e];
    dout = ceout[j * E + e];
    if (e < IDD) did = ceid[j * IDD + e];
  } else {
    int obj = j - MC;
    float sIn = 0.f, sOut = 0.f, sId = 0.f;
    for (int a = 0; a < NATTR; a++) {
      int s = scene[(b * NOBJ + obj) * NATTR + a];
      float m = (s != -1) ? 1.f : 0.f;
      int idx = s + 1;
      sIn  += aein[idx * E + e] * m;
      sOut += aeout[idx * E + e] * m;
      if (e < IDD) sId += aeid[idx * IDD + e] * m;
    }
    din = sIn; dout = sOut; did = sId;
  }
  dendron_bf[(size_t)(b * C + j) * E + e] = f2b(din);
  axon[(size_t)(b * C + j) * E + e] = dout;
  if (e < IDD) {
    identity[(size_t)(b * C + j) * IDD + e]  = did;
    attention[(size_t)(b * C + j) * AD + e]  = att_init[e];
  }
}

// convert axon-MLP weights to bf16 (same layout), meta-MLP weights to transposed fp32
__global__ void k_cvtw(const float* __restrict__ aw1, const float* __restrict__ aw2,
                       const float* __restrict__ mw1, const float* __restrict__ mw2,
                       unsigned short* __restrict__ w1_bf, unsigned short* __restrict__ w2_bf,
                       float* __restrict__ mw1T, float* __restrict__ mw2T) {
  int i = blockIdx.x * 256 + threadIdx.x;     // 192*256 = 49152 threads
  if (i < HD * E)  w1_bf[i] = f2b(aw1[i]);
  if (i < AD * HD) w2_bf[i] = f2b(aw2[i]);
  if (i < 192 * HD) { int c = i / HD, k = i % HD; mw1T[c * HD + k] = mw1[k * 192 + c]; }
  if (i < HD * AD)  { int k = i / AD, a = i % AD; mw2T[k * AD + a] = mw2[a * HD + k]; }
}

// transpose axon (fp32 [j][e]) -> axonT bf16 [e][j]
__global__ __launch_bounds__(256) void k_transA(const float* __restrict__ axon,
                                                unsigned short* __restrict__ axonT) {
  int b = blockIdx.x / 34, jc = blockIdx.x % 34;
  int j0 = jc * 64;
  __shared__ float ax[64][129];
  int tid = threadIdx.x;
  for (int i = tid; i < 64 * E; i += 256) {
    int j = i >> 7, e = i & 127;
    ax[j][e] = axon[(size_t)(b * C + j0 + j) * E + e];
  }
  __syncthreads();
  for (int i = tid; i < E * 64; i += 256) {
    int e = i >> 6, jj = i & 63;
    axonT[(size_t)(b * E + e) * C + j0 + jj] = f2b(ax[jj][e]);
  }
}

// sequential meta scan, coalesced transposed weights
__global__ void k_meta(const int* __restrict__ prog_op, const int* __restrict__ prog_arg,
                       const float* __restrict__ ceout,
                       const float* __restrict__ mw1T, const float* __restrict__ mb1,
                       const float* __restrict__ mw2T, const float* __restrict__ mb2,
                       const float* __restrict__ att_init, float* __restrict__ meta_all) {
  int b = blockIdx.x;
  __shared__ float x[192];
  __shared__ float h[HD];
  __shared__ float meta[AD];
  int tid = threadIdx.x;
  if (tid < AD) meta[tid] = att_init[tid];
  __syncthreads();
  for (int t = 0; t < T; t++) {
    int arg = prog_arg[b * T + t];
    if (tid < AD) x[tid] = meta[tid];
    else if (tid < 192) x[tid] = ceout[arg * E + (tid - 64)];
    __syncthreads();
    float s = mb1[tid];
    for (int c = 0; c < 192; c++) s += x[c] * mw1T[c * HD + tid];
    h[tid] = fmaxf(s, 0.f);
    __syncthreads();
    if (tid < AD) {
      float o = mb2[tid];
      for (int k = 0; k < HD; k++) o += h[k] * mw2T[k * AD + tid];
      float m = (prog_op[b * T + t] == 0) ? 1.f : 0.f;
      float nm = m * o + (1.f - m) * meta[tid];
      meta[tid] = nm;
      meta_all[(t * B + b) * AD + tid] = nm;
    }
    __syncthreads();
  }
}

// proj[t,b,i] = dot(arguments[b,t], axon[b,i]) / E ; one wave per (b,i)
__global__ void k_proj(const int* __restrict__ prog_arg, const float* __restrict__ ceout,
                       const float* __restrict__ axon, float* __restrict__ proj_all) {
  int gid = blockIdx.x * 4 + (threadIdx.x >> 6);
  int lane = threadIdx.x & 63;
  if (gid >= B * C) return;
  int b = gid / C, i = gid % C;
  float a0 = axon[(size_t)(b * C + i) * E + lane];
  float a1 = axon[(size_t)(b * C + i) * E + 64 + lane];
  for (int t = 0; t < T; t++) {
    int arg = prog_arg[b * T + t];
    float p = a0 * ceout[arg * E + lane] + a1 * ceout[arg * E + 64 + lane];
    for (int off = 1; off < 64; off <<= 1) p += __shfl_xor(p, off, 64);
    if (lane == 0) proj_all[(size_t)(t * B + b) * C + i] = p * (1.f / E);
  }
}

// ---------------- per-step kernels ----------------

// siaT[b][d][j] = bf16( ia[b][j][d] * amean[b][j] ), d in [0,128)
__global__ __launch_bounds__(256) void k_sia(const float* __restrict__ identity,
                                             const float* __restrict__ attention,
                                             unsigned short* __restrict__ siaT) {
  int b = blockIdx.x / 34, jc = blockIdx.x % 34;
  int j0 = jc * 64;
  __shared__ float Tt[128][65];
  __shared__ float amL[64];
  int tid = threadIdx.x;
  {
    int j = tid >> 2, q = tid & 3;
    const float4* p = (const float4*)(attention + (size_t)(b * C + j0 + j) * AD + q * 16);
    float4 v0 = p[0], v1 = p[1], v2 = p[2], v3 = p[3];
    float s = v0.x + v0.y + v0.z + v0.w + v1.x + v1.y + v1.z + v1.w
            + v2.x + v2.y + v2.z + v2.w + v3.x + v3.y + v3.z + v3.w;
    s += __shfl_xor(s, 1, 64);
    s += __shfl_xor(s, 2, 64);
    if (q == 0) amL[j] = s * (1.f / AD);
  }
  __syncthreads();
  for (int i = tid; i < 64 * 64; i += 256) {
    int j = i >> 6, d = i & 63;
    Tt[d][j] = identity[(size_t)(b * C + j0 + j) * IDD + d] * amL[j];
  }
  for (int i = tid; i < 64 * 64; i += 256) {
    int j = i >> 6, a = i & 63;
    Tt[64 + a][j] = attention[(size_t)(b * C + j0 + j) * AD + a] * amL[j];
  }
  __syncthreads();
  for (int i = tid; i < 128 * 64; i += 256) {
    int d = i >> 6, jj = i & 63;
    siaT[(size_t)(b * 128 + d) * C + j0 + jj] = f2b(Tt[d][jj]);
  }
}

// Mt[b][d][e] = sum_j siaT[b][d][j] * axonT[b][e][j]   (K = C = 2176, MFMA)
__global__ __launch_bounds__(256) void k_M(const unsigned short* __restrict__ siaT,
                                           const unsigned short* __restrict__ axonT,
                                           unsigned short* __restrict__ Mt) {
  int b = blockIdx.x >> 3, dblk = blockIdx.x & 7;
  int tid = threadIdx.x;
  int w = tid >> 6, lane = tid & 63, lr = lane & 15, lg = lane >> 4;
  int d0 = dblk * 16, e0 = w * 32;
  f32x4 z = {0.f, 0.f, 0.f, 0.f};
  f32x4 acc0 = z, acc1 = z;
  const unsigned short* ap  = siaT  + (size_t)(b * 128 + d0 + lr) * C + lg * 8;
  const unsigned short* bp0 = axonT + (size_t)(b * E + e0 + lr) * C + lg * 8;
  const unsigned short* bp1 = axonT + (size_t)(b * E + e0 + 16 + lr) * C + lg * 8;
  for (int k0 = 0; k0 < C; k0 += 32) {
    s16x8 af = *(const s16x8*)(ap + k0);
    s16x8 b0 = *(const s16x8*)(bp0 + k0);
    s16x8 b1 = *(const s16x8*)(bp1 + k0);
    acc0 = __builtin_amdgcn_mfma_f32_16x16x32_bf16(af, b0, acc0, 0, 0, 0);
    acc1 = __builtin_amdgcn_mfma_f32_16x16x32_bf16(af, b1, acc1, 0, 0, 0);
  }
  #pragma unroll
  for (int v = 0; v < 4; v++) {
    size_t r = (size_t)(b * 128 + d0 + lg * 4 + v) * 128;
    Mt[r + e0 + lr]      = f2b(acc0[v]);
    Mt[r + e0 + 16 + lr] = f2b(acc1[v]);
  }
}

// fused per-step row kernel: gathered (MFMA) -> MLP (MFMA x2) -> update + hist
__global__ __launch_bounds__(256) void k_row(
    int t, const unsigned short* __restrict__ dendron_bf, const unsigned short* __restrict__ Mt,
    const unsigned short* __restrict__ w1_bf, const float* __restrict__ b1g,
    const unsigned short* __restrict__ w2_bf, const float* __restrict__ b2g,
    const float* __restrict__ proj_all, const float* __restrict__ meta_all,
    const int* __restrict__ prog_op, float* __restrict__ attention,
    float* __restrict__ att_hist, float* __restrict__ ins_hist, float* __restrict__ trans_hist) {
  int b = blockIdx.x / 34, tile = blockIdx.x % 34;
  int tid = threadIdx.x;
  int w = tid >> 6, lane = tid & 63, lr = lane & 15, lg = lane >> 4;
  int i0 = tile * 64 + w * 16;
  __shared__ unsigned short g_lds[4][16][136];
  __shared__ unsigned short h_lds[4][16][264];
  f32x4 z = {0.f, 0.f, 0.f, 0.f};

  // ---- phase A: g[16][128] = dendron[i0..i0+16] @ M / C  (Mt is [d][e] = B[col][k]) ----
  {
    s16x8 af[4];
    #pragma unroll
    for (int ke = 0; ke < 4; ke++)
      af[ke] = *(const s16x8*)(dendron_bf + (size_t)(b * C + i0 + lr) * E + ke * 32 + lg * 8);
    #pragma unroll
    for (int n = 0; n < 8; n++) {
      f32x4 acc = z;
      #pragma unroll
      for (int ke = 0; ke < 4; ke++) {
        s16x8 bf = *(const s16x8*)(Mt + (size_t)(b * 128 + n * 16 + lr) * 128 + ke * 32 + lg * 8);
        acc = __builtin_amdgcn_mfma_f32_16x16x32_bf16(af[ke], bf, acc, 0, 0, 0);
      }
      #pragma unroll
      for (int v = 0; v < 4; v++) g_lds[w][lg * 4 + v][n * 16 + lr] = f2b(acc[v] * (1.f / C));
    }
  }
  // ---- phase B: h[16][256] = relu(g @ w1^T + b1)  (w1 natural layout = B[col][k]) ----
  {
    s16x8 gf[4];
    #pragma unroll
    for (int kd = 0; kd < 4; kd++)
      gf[kd] = *(const s16x8*)&g_lds[w][lr][kd * 32 + lg * 8];
    #pragma unroll
    for (int n = 0; n < 16; n++) {
      f32x4 acc = z;
      #pragma unroll
      for (int kd = 0; kd < 4; kd++) {
        s16x8 bf = *(const s16x8*)(w1_bf + (size_t)(n * 16 + lr) * E + kd * 32 + lg * 8);
        acc = __builtin_amdgcn_mfma_f32_16x16x32_bf16(gf[kd], bf, acc, 0, 0, 0);
      }
      float b1v = b1g[n * 16 + lr];
      #pragma unroll
      for (int v = 0; v < 4; v++) h_lds[w][lg * 4 + v][n * 16 + lr] = f2b(fmaxf(acc[v] + b1v, 0.f));
    }
  }
  // ---- phase C: out[16][64] = h @ w2^T ; epilogue ----
  {
    s16x8 hf[8];
    #pragma unroll
    for (int kk = 0; kk < 8; kk++)
      hf[kk] = *(const s16x8*)&h_lds[w][lr][kk * 32 + lg * 8];
    int op = prog_op[b * T + t];
    float insF = (op == 1) ? 1.f : 0.f, trF = (op == 2) ? 1.f : 0.f;
    float projv[4];
    #pragma unroll
    for (int v = 0; v < 4; v++)
      projv[v] = proj_all[(size_t)(t * B + b) * C + i0 + lg * 4 + v];
    #pragma unroll
    for (int n = 0; n < 4; n++) {
      f32x4 acc = z;
      #pragma unroll
      for (int kk = 0; kk < 8; kk++) {
        s16x8 bf = *(const s16x8*)(w2_bf + (size_t)(n * 16 + lr) * HD + kk * 32 + lg * 8);
        acc = __builtin_amdgcn_mfma_f32_16x16x32_bf16(hf[kk], bf, acc, 0, 0, 0);
      }
      int a = n * 16 + lr;
      float b2v = b2g[a];
      float meta_a = meta_all[(size_t)(t * B + b) * AD + a];
      #pragma unroll
      for (int v = 0; v < 4; v++) {
        int row = lg * 4 + v;
        int i = i0 + row;
        float transfer = acc[v] + b2v + b2f(g_lds[w][row][64 + a]);
        float insert = meta_a * projv[v];
        size_t ai = (size_t)(b * C + i) * AD + a;
        float attv = attention[ai] + insF * insert + trF * transfer;
        attv = (attv >= 0.f) ? attv : 0.01f * attv;
        attv = fminf(fmaxf(attv, -1.f), 2.f);
        attention[ai] = attv;
        size_t hi = (((size_t)t * B + b) * C + i) * AD + a;
        att_hist[hi] = attv;
        ins_hist[hi] = insert;
        trans_hist[hi] = transfer;
      }
    }
  }
}

// ---------------- final softmax ----------------
__global__ void k_softmax(const float* __restrict__ attention, float* __restrict__ out) {
  int b = blockIdx.x;
  __shared__ float am[C];
  __shared__ float red[256];
  int tid = threadIdx.x;
  for (int i = tid; i < C; i += 256) {
    float s = 0.f;
    const float* p = attention + (size_t)(b * C + i) * AD;
    for (int a = 0; a < AD; a++) s += p[a];
    am[i] = s * (1.f / AD);
  }
  __syncthreads();
  float mx = -1e30f;
  for (int i = tid; i < C; i += 256) mx = fmaxf(mx, am[i]);
  red[tid] = mx; __syncthreads();
  for (int s = 128; s > 0; s >>= 1) { if (tid < s) red[tid] = fmaxf(red[tid], red[tid + s]); __syncthreads(); }
  mx = red[0]; __syncthreads();
  float sm = 0.f;
  for (int i = tid; i < C; i += 256) sm += expf(am[i] - mx);
  red[tid] = sm; __syncthreads();
  for (int s = 128; s > 0; s >>= 1) { if (tid < s) red[tid] += red[tid + s]; __syncthreads(); }
  float lse = logf(red[0]) + mx;
  for (int i = tid; i < C; i += 256) out[(size_t)b * C + i] = am[i] - lse;
}

extern "C" void kernel_launch(void* const* d_in, const int* in_sizes, int n_in,
                              void* d_out, int out_size, void* d_ws, size_t ws_size,
                              hipStream_t stream) {
  const int* scene     = (const int*)d_in[0];
  const int* prog_op   = (const int*)d_in[1];
  const int* prog_arg  = (const int*)d_in[2];
  const float* aein    = (const float*)d_in[3];
  const float* aeout   = (const float*)d_in[4];
  const float* aeid    = (const float*)d_in[5];
  const float* cein    = (const float*)d_in[6];
  const float* ceout   = (const float*)d_in[7];
  const float* ceid    = (const float*)d_in[8];
  const float* att_init = (const float*)d_in[11];
  const float* aw1 = (const float*)d_in[12];
  const float* ab1 = (const float*)d_in[13];
  const float* aw2 = (const float*)d_in[14];
  const float* ab2 = (const float*)d_in[15];
  const float* mw1 = (const float*)d_in[16];
  const float* mb1 = (const float*)d_in[17];
  const float* mw2 = (const float*)d_in[18];
  const float* mb2 = (const float*)d_in[19];

  char* ws = (char*)d_ws;
  size_t off = 0;
  auto carve = [&](size_t bytes) { char* p = ws + off; off += (bytes + 255) & ~(size_t)255; return p; };
  float* axon      = (float*)carve((size_t)B * C * E * 4);
  float* identity  = (float*)carve((size_t)B * C * IDD * 4);
  float* attention = (float*)carve((size_t)B * C * AD * 4);
  float* proj_all  = (float*)carve((size_t)T * B * C * 4);
  float* meta_all  = (float*)carve((size_t)T * B * AD * 4);
  float* mw1T      = (float*)carve((size_t)192 * HD * 4);
  float* mw2T      = (float*)carve((size_t)HD * AD * 4);
  unsigned short* dendron_bf = (unsigned short*)carve((size_t)B * C * E * 2);
  unsigned short* axonT      = (unsigned short*)carve((size_t)B * E * C * 2);
  unsigned short* siaT       = (unsigned short*)carve((size_t)B * 128 * C * 2);
  unsigned short* Mt         = (unsigned short*)carve((size_t)B * E * E * 2);
  unsigned short* w1_bf      = (unsigned short*)carve((size_t)HD * E * 2);
  unsigned short* w2_bf      = (unsigned short*)carve((size_t)AD * HD * 2);

  float* out_sm     = (float*)d_out;
  float* att_hist   = out_sm + B * C;
  float* ins_hist   = att_hist + (size_t)T * B * C * AD;
  float* trans_hist = ins_hist + (size_t)T * B * C * AD;

  k_build<<<dim3(B * C), dim3(E), 0, stream>>>(scene, aein, aeout, aeid, cein, ceout, ceid,
                                               att_init, dendron_bf, axon, identity, attention);
  k_cvtw<<<dim3(192), dim3(256), 0, stream>>>(aw1, aw2, mw1, mw2, w1_bf, w2_bf, mw1T, mw2T);
  k_transA<<<dim3(B * 34), dim3(256), 0, stream>>>(axon, axonT);
  k_meta<<<dim3(B), dim3(256), 0, stream>>>(prog_op, prog_arg, ceout, mw1T, mb1, mw2T, mb2,
                                            att_init, meta_all);
  k_proj<<<dim3(B * C / 4), dim3(256), 0, stream>>>(prog_arg, ceout, axon, proj_all);

  for (int t = 0; t < T; t++) {
    k_sia<<<dim3(B * 34), dim3(256), 0, stream>>>(identity, attention, siaT);
    k_M<<<dim3(B * 8), dim3(256), 0, stream>>>(siaT, axonT, Mt);
    k_row<<<dim3(B * 34), dim3(256), 0, stream>>>(t, dendron_bf, Mt, w1_bf, ab1, w2_bf, ab2,
                                                  proj_all, meta_all, prog_op, attention,
                                                  att_hist, ins_hist, trans_hist);
  }
  k_softmax<<<dim3(B), dim3(256), 0, stream>>>(attention, out_sm);
}